// Round 7
// baseline (294.017 us; speedup 1.0000x reference)
//
#include <hip/hip_runtime.h>
#include <math.h>

#define B_  4
#define N_  2048
#define C_  1024
#define H_  16
#define HD_ 64
#define C3_ (3 * C_)
// 0.125 * log2(e): fold softmax base-e into Q (via qkv_w rows 0..1023) to use native exp2
#define QSCALE_ 0.18033688011112042f

// fused-cast segment sizes in 8-element groups
#define NX8_  1048576   // x:      8388608 / 8
#define NWQ8_  393216   // qkv_w:  3145728 / 8
#define NWP8_  131072   // proj_w: 1048576 / 8
#define QS8_   131072   // scaled prefix of qkv_w (first C*C elems)

typedef float f32x4  __attribute__((ext_vector_type(4)));
typedef float f32x16 __attribute__((ext_vector_type(16)));
typedef short short8 __attribute__((ext_vector_type(8)));
typedef unsigned short ushort8 __attribute__((ext_vector_type(8)));
typedef unsigned int uint2v __attribute__((ext_vector_type(2)));

__device__ inline unsigned short f2bf(float f) {   // RNE f32 -> bf16
    union { float f; unsigned u; } v; v.f = f;
    unsigned r = v.u + 0x7fffu + ((v.u >> 16) & 1u);
    return (unsigned short)(r >> 16);
}

__device__ inline unsigned cvtpk_bf16(float lo, float hi) {   // (hi<<16)|lo as bf16 pair
    unsigned r;
    asm("v_cvt_pk_bf16_f32 %0, %1, %2" : "=v"(r) : "v"(lo), "v"(hi));
    return r;
}

// async global -> LDS, 16B per lane. lptr = WAVE-uniform base; lane l lands at base+l*16.
#define GLD16(gptr, lptr) \
    __builtin_amdgcn_global_load_lds((const __attribute__((address_space(1))) unsigned int*)(gptr), \
                                     (__attribute__((address_space(3))) unsigned int*)(lptr), 16, 0, 0)

// ============================================================================
// Fused cast fp32 -> bf16 for x, qkv_w (Q-rows pre-scaled), proj_w.
// Output regions are contiguous in ws starting at `out`.
// ============================================================================
__global__ __launch_bounds__(256) void cast_all_k(const float* __restrict__ x,
                                                  const float* __restrict__ wq,
                                                  const float* __restrict__ wp,
                                                  unsigned short* __restrict__ out) {
    int i = blockIdx.x * 256 + threadIdx.x;      // 8-elem group id, grid covers exactly
    const float* src;
    float sc = 1.0f;
    if (i < NX8_) {
        src = x + (size_t)i * 8;
    } else if (i < NX8_ + NWQ8_) {
        int j = i - NX8_;
        src = wq + (size_t)j * 8;
        if (j < QS8_) sc = QSCALE_;
    } else {
        int j = i - NX8_ - NWQ8_;
        src = wp + (size_t)j * 8;
    }
    float4 a = ((const float4*)src)[0], b = ((const float4*)src)[1];
    ushort8 o;
    o[0]=f2bf(a.x*sc); o[1]=f2bf(a.y*sc); o[2]=f2bf(a.z*sc); o[3]=f2bf(a.w*sc);
    o[4]=f2bf(b.x*sc); o[5]=f2bf(b.y*sc); o[6]=f2bf(b.z*sc); o[7]=f2bf(b.w*sc);
    *((ushort8*)out + i) = o;
}

// ============================================================================
// 128x128xK bf16 MFMA core, BK=32, double-buffered global_load_lds prefetch.
// Chunk-swizzled LDS: slot (row, ca) holds logical chunk ca ^ ((row>>1)&3).
// ============================================================================
__device__ inline void gemm128_core(const unsigned short* __restrict__ A,
                                    const unsigned short* __restrict__ Bm,
                                    int m0, int n0, int K,
                                    char* smem,
                                    f32x4 acc[4][4])
{
    const int tid = threadIdx.x;
    const int lane = tid & 63, w = tid >> 6;
    const int lg = lane >> 4, lr = lane & 15;
    const int wr = (w >> 1) * 64, wc = (w & 1) * 64;
    const int srow = tid >> 2;
    const int scs = (tid & 3) ^ ((srow >> 1) & 3);       // pre-swizzled source chunk
    const int lgx = lg ^ ((lr >> 1) & 3);                // swizzled read chunk
    const unsigned wbase = (unsigned)(tid & 192) * 16;   // w*1024

    const unsigned short* pa0 = &A[(size_t)(m0 + srow) * K + scs * 8];
    const unsigned short* pa1 = &A[(size_t)(m0 + srow + 64) * K + scs * 8];
    const unsigned short* pb0 = &Bm[(size_t)(n0 + srow) * K + scs * 8];
    const unsigned short* pb1 = &Bm[(size_t)(n0 + srow + 64) * K + scs * 8];

    // prologue: tile 0 -> buffer 0
    GLD16(pa0, smem + wbase);
    GLD16(pa1, smem + 4096 + wbase);
    GLD16(pb0, smem + 16384 + wbase);
    GLD16(pb1, smem + 16384 + 4096 + wbase);

    const int NT = K / 32;
    for (int t = 0; t < NT; ++t) {
        __syncthreads();                                 // drains vmcnt: buf[t&1] ready
        const unsigned cur = (unsigned)(t & 1) * 8192;
        if (t + 1 < NT) {
            const unsigned nxt = 8192 - cur;
            const int ko = (t + 1) * 32;
            GLD16(pa0 + ko, smem + nxt + wbase);
            GLD16(pa1 + ko, smem + nxt + 4096 + wbase);
            GLD16(pb0 + ko, smem + 16384 + nxt + wbase);
            GLD16(pb1 + ko, smem + 16384 + nxt + 4096 + wbase);
        }
        const unsigned short* cA = (const unsigned short*)(smem + cur);
        const unsigned short* cB = (const unsigned short*)(smem + 16384 + cur);
        short8 af[4], bf[4];
#pragma unroll
        for (int i = 0; i < 4; ++i) {
            af[i] = *(const short8*)&cA[(wr + i*16 + lr) * 32 + lgx * 8];
            bf[i] = *(const short8*)&cB[(wc + i*16 + lr) * 32 + lgx * 8];
        }
#pragma unroll
        for (int i = 0; i < 4; ++i)
#pragma unroll
            for (int j = 0; j < 4; ++j)
                acc[i][j] = __builtin_amdgcn_mfma_f32_16x16x32_bf16(af[i], bf[j], acc[i][j], 0, 0, 0);
    }
}

// ============================================================================
// QKV GEMM (bf16): out plain [8192][3072] bf16 (QSCALE pre-folded into weights).
// XCD-swizzled flat grid: each XCD owns an 8-wide bx octet (A-slice L2-resident).
// ============================================================================
__global__ __launch_bounds__(256) void qkv_gemm_k(const unsigned short* __restrict__ x,
                                                  const unsigned short* __restrict__ w,
                                                  unsigned short* __restrict__ outp) {
    __shared__ __align__(16) char smem[32768];
    f32x4 acc[4][4];
    f32x4 z = {0.f, 0.f, 0.f, 0.f};
#pragma unroll
    for (int i = 0; i < 4; ++i)
#pragma unroll
        for (int j = 0; j < 4; ++j) acc[i][j] = z;

    // fid -> (bx, by): xcd = fid&7 owns bx in [xcd*8, xcd*8+8), all by
    const int fid = blockIdx.x;
    const int xcd = fid & 7, sub = fid >> 3;
    const int m0 = (xcd * 8 + (sub & 7)) * 128;
    const int n0 = (sub >> 3) * 128;
    gemm128_core(x, w, m0, n0, C_, smem, acc);

    const int tid = threadIdx.x, lane = tid & 63, w4 = tid >> 6;
    const int lg = lane >> 4, lr = lane & 15;
    const int wc = (w4 & 1) * 64;
    const int myhalf = w4 >> 1;                 // wr = myhalf*64
    unsigned short* ep = (unsigned short*)smem; // [64][136]

    for (int half = 0; half < 2; ++half) {
        __syncthreads();
        if (myhalf == half) {
#pragma unroll
            for (int mi = 0; mi < 4; ++mi)
#pragma unroll
                for (int ni = 0; ni < 4; ++ni) {
                    const int col = wc + ni * 16 + lr;
                    const int r0 = mi * 16 + lg * 4;
                    unsigned p01 = cvtpk_bf16(acc[mi][ni][0], acc[mi][ni][1]);
                    unsigned p23 = cvtpk_bf16(acc[mi][ni][2], acc[mi][ni][3]);
                    ep[(r0 + 0) * 136 + col] = (unsigned short)p01;
                    ep[(r0 + 1) * 136 + col] = (unsigned short)(p01 >> 16);
                    ep[(r0 + 2) * 136 + col] = (unsigned short)p23;
                    ep[(r0 + 3) * 136 + col] = (unsigned short)(p23 >> 16);
                }
        }
        __syncthreads();
#pragma unroll
        for (int it = 0; it < 4; ++it) {
            int id = it * 256 + tid;             // 0..1023 = 64 rows x 16 chunks
            int rl = id >> 4, ch = id & 15;
            ushort8 o = *(const ushort8*)&ep[rl * 136 + ch * 8];
            *(ushort8*)&outp[(size_t)(m0 + half * 64 + rl) * C3_ + n0 + ch * 8] = o;
        }
    }
}

// ============================================================================
// V -> V^T : qkvp[tok][2048 + h*64 + d]  ->  vt[b][h][d][n]
// ============================================================================
__global__ __launch_bounds__(256) void vtrans_k(const unsigned short* __restrict__ qkvp,
                                                unsigned short* __restrict__ vt) {
    __shared__ unsigned short st[64 * 72];
    const int tid = threadIdx.x;
    const int n0 = blockIdx.x * 64;
    const int bh = blockIdx.y;
    const int bb = bh >> 4, hh = bh & 15;
    const unsigned short* V = qkvp + (size_t)bb * N_ * C3_ + 2 * C_ + hh * HD_;
    unsigned short* VT = vt + (size_t)bh * HD_ * N_;
    const int r = tid >> 2, c = tid & 3;
    ushort8 v0 = *(const ushort8*)&V[(size_t)(n0 + r) * C3_ + c * 8];
    ushort8 v1 = *(const ushort8*)&V[(size_t)(n0 + r) * C3_ + (c + 4) * 8];
    *(ushort8*)&st[r * 72 + c * 8] = v0;
    *(ushort8*)&st[r * 72 + (c + 4) * 8] = v1;
    __syncthreads();
#pragma unroll
    for (int cc = 0; cc < 2; ++cc) {
        int ch = c + cc * 4;
        ushort8 o;
#pragma unroll
        for (int j = 0; j < 8; ++j) o[j] = st[(ch * 8 + j) * 72 + r];
        *(ushort8*)&VT[(size_t)r * N_ + n0 + ch * 8] = o;
    }
}

// ============================================================================
// MFMA flash attention, 32x32x16, in-register P, no-max softmax, dbuf prefetch,
// conflict-free swizzle, XCD-bijective block swizzle (8 whole (b,h) per XCD).
// ============================================================================
__global__ __launch_bounds__(256) void attn_k(const unsigned short* __restrict__ qkvp,
                                              const unsigned short* __restrict__ vt,
                                              unsigned short* __restrict__ aout) {
    __shared__ __align__(16) char smem[32768];
    // buffer b at smem + b*16384:  K tile [64][64] @ +0, V^T tile [64][64] @ +8192

    const int tid = threadIdx.x, lane = tid & 63, w = tid >> 6;
    const int q31 = lane & 31, hi = lane >> 5;

    // XCD swizzle: id%8 = XCD -> give it contiguous swz chunk = 8 whole (b,h)
    const int id = blockIdx.x;
    const int swz = (id & 7) * 128 + (id >> 3);
    const int b = swz >> 8, h = (swz >> 4) & 15, qt = swz & 15;

    const unsigned short* Qrow = qkvp + (size_t)(b * N_ + qt * 128 + w * 32 + q31) * C3_ + h * HD_;
    const unsigned short* Kbase = qkvp + (size_t)(b * N_) * C3_ + C_ + h * HD_;
    const unsigned short* VT = vt + ((size_t)b * H_ + h) * ((size_t)HD_ * N_);

    // Q fragments (B-operand): lane&31 = q, k = ks*16 + hi*8 + j
    short8 qf[4];
#pragma unroll
    for (int ks = 0; ks < 4; ++ks)
        qf[ks] = *(const short8*)&Qrow[ks * 16 + hi * 8];

    f32x16 O0, O1, z16;
#pragma unroll
    for (int r = 0; r < 16; ++r) { O0[r] = 0.f; O1[r] = 0.f; z16[r] = 0.f; }
    float l_lane = 0.f;

    // staging: lane slot = byte tid*16 -> (row = tid>>3, chunk_addr = tid&7);
    // slot (row,ca) holds logical chunk ca ^ (row&7) ^ ((row>>3)&3)
    const int srow = tid >> 3;
    const int scs = (tid & 7) ^ (srow & 7) ^ ((srow >> 3) & 3);
    const unsigned wbase = (unsigned)(tid & 192) * 16;   // w*1024

    const unsigned short* Ksrc = Kbase + (size_t)srow * C3_ + scs * 8;
    const unsigned short* Vsrc = VT + (size_t)srow * N_ + scs * 8;

    // fragment byte offsets within a tile (same XOR for rows q31 and 32+q31)
    const int xq = (q31 & 7) ^ ((q31 >> 3) & 3);
    int fo[4];
#pragma unroll
    for (int ks = 0; ks < 4; ++ks)
        fo[ks] = q31 * 128 + (((2 * ks + hi) ^ xq) * 16);

    // prologue: tile 0 -> buffer 0
    GLD16(Ksrc,                          smem + wbase);
    GLD16(Ksrc + (size_t)32 * C3_,       smem + 4096 + wbase);
    GLD16(Vsrc,                          smem + 8192 + wbase);
    GLD16(Vsrc + (size_t)32 * N_,        smem + 12288 + wbase);

    const int NT = N_ / 64;
    for (int t = 0; t < NT; ++t) {
        __syncthreads();                                 // buf[t&1] ready; prev reads done
        const unsigned cur = (unsigned)(t & 1) * 16384;
        if (t + 1 < NT) {
            const unsigned nxt = 16384 - cur;
            const size_t k1 = (size_t)(t + 1) * 64;
            GLD16(Ksrc + k1 * C3_,              smem + nxt + wbase);
            GLD16(Ksrc + (k1 + 32) * C3_,       smem + nxt + 4096 + wbase);
            GLD16(Vsrc + k1,                    smem + nxt + 8192 + wbase);
            GLD16(Vsrc + k1 + (size_t)32 * N_,  smem + nxt + 12288 + wbase);
        }
        const char* sK = smem + cur;
        const char* sV = smem + cur + 8192;

        // ---- S^T = K Q^T  (first MFMA consumes loop-invariant zero C) ----
        f32x16 S0, S1;
        __builtin_amdgcn_s_setprio(1);
        {
            short8 kfa = *(const short8*)(sK + fo[0]);
            short8 kfb = *(const short8*)(sK + 4096 + fo[0]);
            S0 = __builtin_amdgcn_mfma_f32_32x32x16_bf16(kfa, qf[0], z16, 0, 0, 0);
            S1 = __builtin_amdgcn_mfma_f32_32x32x16_bf16(kfb, qf[0], z16, 0, 0, 0);
        }
#pragma unroll
        for (int ks = 1; ks < 4; ++ks) {
            short8 kfa = *(const short8*)(sK + fo[ks]);
            short8 kfb = *(const short8*)(sK + 4096 + fo[ks]);
            S0 = __builtin_amdgcn_mfma_f32_32x32x16_bf16(kfa, qf[ks], S0, 0, 0, 0);
            S1 = __builtin_amdgcn_mfma_f32_32x32x16_bf16(kfb, qf[ks], S1, 0, 0, 0);
        }
        __builtin_amdgcn_s_setprio(0);

        // ---- no-max softmax: P = exp2(S), accumulate l per-lane ----
        float rs = 0.f;
#pragma unroll
        for (int r = 0; r < 16; ++r) {
            float p0 = __builtin_amdgcn_exp2f(S0[r]);
            float p1 = __builtin_amdgcn_exp2f(S1[r]);
            S0[r] = p0; S1[r] = p1;
            rs += p0 + p1;
        }
        l_lane += rs;

        // ---- P -> bf16 PV B-fragments in-register (cvt_pk + permlane32_swap) ----
        short8 pB[4];
#pragma unroll
        for (int ksk = 0; ksk < 4; ++ksk) {
            const int off = (ksk & 1) * 8;
            float e0, e1, e2, e3, e4, e5, e6, e7;
            if (ksk < 2) { e0=S0[off+0]; e1=S0[off+1]; e2=S0[off+2]; e3=S0[off+3];
                           e4=S0[off+4]; e5=S0[off+5]; e6=S0[off+6]; e7=S0[off+7]; }
            else         { e0=S1[off+0]; e1=S1[off+1]; e2=S1[off+2]; e3=S1[off+3];
                           e4=S1[off+4]; e5=S1[off+5]; e6=S1[off+6]; e7=S1[off+7]; }
            unsigned a_ = cvtpk_bf16(e0, e1);
            unsigned b_ = cvtpk_bf16(e4, e5);
            unsigned c_ = cvtpk_bf16(e2, e3);
            unsigned d_ = cvtpk_bf16(e6, e7);
            uint2v r1 = __builtin_amdgcn_permlane32_swap(a_, b_, false, false);
            uint2v r2 = __builtin_amdgcn_permlane32_swap(c_, d_, false, false);
            union { unsigned u[4]; short8 s; } uu;
            uu.u[0] = r1[0]; uu.u[1] = r2[0]; uu.u[2] = r1[1]; uu.u[3] = r2[1];
            pB[ksk] = uu.s;
        }

        // ---- O^T += V^T P ----
        __builtin_amdgcn_s_setprio(1);
#pragma unroll
        for (int ksk = 0; ksk < 4; ++ksk) {
            short8 va0 = *(const short8*)(sV + fo[ksk]);
            short8 va1 = *(const short8*)(sV + 4096 + fo[ksk]);
            O0 = __builtin_amdgcn_mfma_f32_32x32x16_bf16(va0, pB[ksk], O0, 0, 0, 0);
            O1 = __builtin_amdgcn_mfma_f32_32x32x16_bf16(va1, pB[ksk], O1, 0, 0, 0);
        }
        __builtin_amdgcn_s_setprio(0);
    }

    // ---- epilogue: normalize, cvt_pk pairs -> LDS bounce -> coalesced stores ----
    float l = l_lane + __shfl_xor(l_lane, 32);
    __syncthreads();
    unsigned short* epi = (unsigned short*)smem;   // [128][72]
    {
        float inv = 1.0f / l;
        const int row = w * 32 + q31;
#pragma unroll
        for (int g = 0; g < 4; ++g) {
            int col0 = 8 * g + 4 * hi;
            *(unsigned*)&epi[row * 72 + col0]          = cvtpk_bf16(O0[4*g+0]*inv, O0[4*g+1]*inv);
            *(unsigned*)&epi[row * 72 + col0 + 2]      = cvtpk_bf16(O0[4*g+2]*inv, O0[4*g+3]*inv);
            *(unsigned*)&epi[row * 72 + 32 + col0]     = cvtpk_bf16(O1[4*g+0]*inv, O1[4*g+1]*inv);
            *(unsigned*)&epi[row * 72 + 32 + col0 + 2] = cvtpk_bf16(O1[4*g+2]*inv, O1[4*g+3]*inv);
        }
    }
    __syncthreads();
#pragma unroll
    for (int it = 0; it < 4; ++it) {
        int id2 = it * 256 + tid;
        int tk = id2 >> 3, dc = id2 & 7;
        ushort8 o = *(const ushort8*)&epi[tk * 72 + dc * 8];
        *(ushort8*)&aout[((size_t)b * N_ + qt * 128 + tk) * C_ + h * HD_ + dc * 8] = o;
    }
}

// ============================================================================
// proj GEMM (bf16 in, fp32 out + bias), XCD-swizzled flat grid (512 blocks)
// ============================================================================
__global__ __launch_bounds__(256) void proj_gemm_k(const unsigned short* __restrict__ a,
                                                   const unsigned short* __restrict__ w,
                                                   const float* __restrict__ bias,
                                                   float* __restrict__ out) {
    __shared__ __align__(16) char smem[32768];
    f32x4 acc[4][4];
    f32x4 z = {0.f, 0.f, 0.f, 0.f};
#pragma unroll
    for (int i = 0; i < 4; ++i)
#pragma unroll
        for (int j = 0; j < 4; ++j) acc[i][j] = z;

    const int fid = blockIdx.x;
    const int xcd = fid & 7, sub = fid >> 3;      // sub 0..63
    const int m0 = (xcd * 8 + (sub & 7)) * 128;
    const int n0 = (sub >> 3) * 128;
    gemm128_core(a, w, m0, n0, C_, smem, acc);

    const int lane = threadIdx.x & 63, w4 = threadIdx.x >> 6;
    const int lg = lane >> 4, lr = lane & 15;
    const int wr = (w4 >> 1) * 64, wc = (w4 & 1) * 64;
#pragma unroll
    for (int mi = 0; mi < 4; ++mi)
#pragma unroll
        for (int ni = 0; ni < 4; ++ni) {
            int ch = n0 + wc + ni * 16 + lr;
            float bv = bias[ch];
#pragma unroll
            for (int r = 0; r < 4; ++r) {
                int tok = m0 + wr + mi * 16 + lg * 4 + r;
                out[(size_t)tok * C_ + ch] = acc[mi][ni][r] + bv;
            }
        }
}

// ============================================================================
extern "C" void kernel_launch(void* const* d_in, const int* in_sizes, int n_in,
                              void* d_out, int out_size, void* d_ws, size_t ws_size,
                              hipStream_t stream) {
    const float* x      = (const float*)d_in[0];
    const float* qkv_w  = (const float*)d_in[1];
    const float* proj_w = (const float*)d_in[2];
    const float* proj_b = (const float*)d_in[3];
    float* out = (float*)d_out;

    unsigned short* x_bf    = (unsigned short*)d_ws;
    unsigned short* wqkv_bf = x_bf + (size_t)B_ * N_ * C_;
    unsigned short* wproj_bf= wqkv_bf + (size_t)3 * C_ * C_;
    unsigned short* qkvp    = wproj_bf + (size_t)C_ * C_;          // [8192][3072]
    unsigned short* vt      = qkvp + (size_t)B_ * N_ * C3_;        // [b][h][d][n]
    unsigned short* attn    = vt + (size_t)B_ * H_ * HD_ * N_;     // [8192][1024]

    const int ncast = NX8_ + NWQ8_ + NWP8_;       // 1572864 groups
    cast_all_k<<<ncast / 256, 256, 0, stream>>>(x, qkv_w, proj_w, x_bf);

    qkv_gemm_k<<<1536, 256, 0, stream>>>(x_bf, wqkv_bf, qkvp);
    vtrans_k<<<dim3(N_ / 64, B_ * H_), 256, 0, stream>>>(qkvp, vt);
    attn_k<<<1024, 256, 0, stream>>>(qkvp, vt, attn);
    proj_gemm_k<<<512, 256, 0, stream>>>(attn, wproj_bf, proj_b, out);
}